// Round 5
// baseline (193.062 us; speedup 1.0000x reference)
//
#include <hip/hip_runtime.h>
#include <math.h>

#define B 16
#define C 512
#define L 8192
#define PP 128
#define TL 64                      // l-positions per softmax tile
#define TPB 4                      // tiles per block sweep
#define NB (L / (TL * TPB))        // 32 partial-blocks per batch
#define LN_EPS 1e-5f

typedef float fx4 __attribute__((ext_vector_type(4)));

// ---- Fused: scores + running flash softmax + partial context, registers only. ----
// Grid (NB, B), 1024 threads. Thread: q = tid&15 (l = 4q..4q+3), r = tid>>4 (0..63),
// rows c = r + 64*i (i<8). Per tile: 8 float4 loads held in registers, reused for
// scores (reduce over c) and weighted context (accumulated privately, reduced once).
__global__ __launch_bounds__(1024) void k_fused(
    const float* __restrict__ x, const float* __restrict__ cw,
    float* __restrict__ part_pc, float* __restrict__ part_m, float* __restrict__ part_z) {
  const int b = blockIdx.y;
  const int blk = blockIdx.x;
  const int tid = threadIdx.x;
  const int q = tid & 15;
  const int r = tid >> 4;
  const int lane = tid & 63;
  const int w = tid >> 6;

  __shared__ float scw[C];
  __shared__ float sred[16][TL] __attribute__((aligned(16)));
  __shared__ float pw[TL] __attribute__((aligned(16)));
  __shared__ float s_m, s_z, s_resc;

  if (tid < C) scw[tid] = cw[tid];
  if (tid == 0) { s_m = -INFINITY; s_z = 0.f; }
  __syncthreads();

  float pc[8] = {0.f, 0.f, 0.f, 0.f, 0.f, 0.f, 0.f, 0.f};
  const fx4* x4 = (const fx4*)(x + (size_t)b * C * L);
  const int col0 = blk * TPB * (TL / 4) + q;

  fx4 bufA[8], bufB[8];

  // preload tile 0
  #pragma unroll
  for (int i = 0; i < 8; ++i)
    bufA[i] = x4[(size_t)(r + 64 * i) * (L / 4) + col0];

  auto tile_step = [&](fx4* xv, fx4* xn, int t) {
    // phase 1: per-thread score partials from registers
    float sp0 = 0.f, sp1 = 0.f, sp2 = 0.f, sp3 = 0.f;
    #pragma unroll
    for (int i = 0; i < 8; ++i) {
      const float wc = scw[r + 64 * i];
      sp0 += xv[i].x * wc; sp1 += xv[i].y * wc;
      sp2 += xv[i].z * wc; sp3 += xv[i].w * wc;
    }
    // reduce over r within wave (lane bits 4..5)
    #pragma unroll
    for (int m = 16; m <= 32; m <<= 1) {
      sp0 += __shfl_xor(sp0, m); sp1 += __shfl_xor(sp1, m);
      sp2 += __shfl_xor(sp2, m); sp3 += __shfl_xor(sp3, m);
    }
    if (lane < 16) {
      fx4 v; v.x = sp0; v.y = sp1; v.z = sp2; v.w = sp3;
      ((fx4*)&sred[w][0])[lane] = v;
    }
    // prefetch next tile before the barrier (hides HBM latency under softmax+phase2)
    if (t + 1 < TPB) {
      const int col = col0 + (t + 1) * (TL / 4);
      #pragma unroll
      for (int i = 0; i < 8; ++i)
        xn[i] = x4[(size_t)(r + 64 * i) * (L / 4) + col];
    }
    __syncthreads();

    // wave 0: finalize 64 scores, online softmax update
    if (tid < 64) {
      float s = 0.f;
      #pragma unroll
      for (int g = 0; g < 16; ++g) s += sred[g][tid];
      float m = s;
      #pragma unroll
      for (int off = 32; off; off >>= 1) m = fmaxf(m, __shfl_xor(m, off));
      const float mold = s_m;
      const float mnew = fmaxf(mold, m);
      const float p = __expf(s - mnew);
      float z = p;
      #pragma unroll
      for (int off = 32; off; off >>= 1) z += __shfl_xor(z, off);
      pw[tid] = p;
      if (tid == 0) {
        const float e = __expf(mold - mnew);   // t=0: exp(-inf)=0
        s_resc = e;
        s_z = s_z * e + z;
        s_m = mnew;
      }
    }
    __syncthreads();

    // phase 2: private weighted accumulation (no cross-lane here)
    const float resc = s_resc;
    const fx4 w4 = ((const fx4*)pw)[q];
    #pragma unroll
    for (int i = 0; i < 8; ++i) {
      const float pv = xv[i].x * w4.x + xv[i].y * w4.y + xv[i].z * w4.z + xv[i].w * w4.w;
      pc[i] = pc[i] * resc + pv;
    }
  };

  tile_step(bufA, bufB, 0);
  tile_step(bufB, bufA, 1);
  tile_step(bufA, bufB, 2);
  tile_step(bufB, bufA, 3);

  // one-time reduce over q (lane bits 0..3)
  #pragma unroll
  for (int m = 1; m <= 8; m <<= 1) {
    #pragma unroll
    for (int i = 0; i < 8; ++i) pc[i] += __shfl_xor(pc[i], m);
  }
  if (q == 0) {
    float* dst = part_pc + (size_t)(b * NB + blk) * C;
    #pragma unroll
    for (int i = 0; i < 8; ++i) dst[r + 64 * i] = pc[i];
  }
  if (tid == 0) {
    part_m[b * NB + blk] = s_m;
    part_z[b * NB + blk] = s_z;
  }
}

// ---- Tail: flash-combine 32 partials -> context -> MLP(LN,ReLU) -> add_term ----
__global__ void k_tail(const float* __restrict__ part_pc, const float* __restrict__ part_m,
                       const float* __restrict__ part_z,
                       const float* __restrict__ w1, const float* __restrict__ b1,
                       const float* __restrict__ lnw, const float* __restrict__ lnb,
                       const float* __restrict__ w2, const float* __restrict__ b2,
                       float* __restrict__ add_term) {
  const int b = blockIdx.x;
  const int tid = threadIdx.x;   // 512 threads
  __shared__ float se[NB];
  __shared__ float sctx[C];
  __shared__ float st[PP];

  if (tid < 64) {
    const float m = (tid < NB) ? part_m[b * NB + tid] : -INFINITY;
    float M = m;
    #pragma unroll
    for (int off = 16; off; off >>= 1) M = fmaxf(M, __shfl_xor(M, off, 32));
    const float e = (tid < NB) ? __expf(m - M) : 0.f;
    float Z = (tid < NB) ? part_z[b * NB + tid] * e : 0.f;
    #pragma unroll
    for (int off = 16; off; off >>= 1) Z += __shfl_xor(Z, off, 32);
    if (tid < NB) se[tid] = e / Z;
  }
  __syncthreads();

  // context[b, tid]
  float acc = 0.f;
  const float* pp = part_pc + (size_t)b * NB * C + tid;
  #pragma unroll
  for (int t = 0; t < NB; ++t) acc += pp[(size_t)t * C] * se[t];
  sctx[tid] = acc;
  __syncthreads();

  // t = w1 @ ctx + b1 (4 threads per output p)
  {
    const int p = tid >> 2;
    const int qq = tid & 3;
    const float* w1r = w1 + (size_t)p * C + qq * 128;
    const float* cx = &sctx[qq * 128];
    float a = 0.f;
    #pragma unroll 8
    for (int cc = 0; cc < 128; ++cc) a += w1r[cc] * cx[cc];
    a += __shfl_xor(a, 1);
    a += __shfl_xor(a, 2);
    if (qq == 0) st[p] = a + b1[p];
  }
  __syncthreads();

  // LayerNorm over P + ReLU
  float tv = 0.f;
  if (tid < PP) {
    float mu = 0.f;
    #pragma unroll 8
    for (int pi = 0; pi < PP; ++pi) mu += st[pi];
    mu *= (1.f / PP);
    float var = 0.f;
    #pragma unroll 8
    for (int pi = 0; pi < PP; ++pi) { const float d = st[pi] - mu; var += d * d; }
    var *= (1.f / PP);
    tv = (st[tid] - mu) * rsqrtf(var + LN_EPS) * lnw[tid] + lnb[tid];
    tv = fmaxf(tv, 0.f);
  }
  __syncthreads();
  if (tid < PP) st[tid] = tv;
  __syncthreads();

  // add_term[c] = w2[c,:] @ t + b2[c]
  float a2 = b2[tid];
  const float* w2r = w2 + (size_t)tid * PP;
  #pragma unroll 8
  for (int pi = 0; pi < PP; ++pi) a2 += w2r[pi] * st[pi];
  add_term[b * C + tid] = a2;
}

// ---- out[b,c,:] = x[b,c,:] + add_term[b,c]; NT stores keep x resident in L3 ----
__global__ void k_add(const float* __restrict__ x, const float* __restrict__ at,
                      float* __restrict__ out) {
  const int bc = blockIdx.x;
  const float a = at[bc];
  const fx4* xr = (const fx4*)(x + (size_t)bc * L);
  fx4* orow = (fx4*)(out + (size_t)bc * L);
  #pragma unroll 4
  for (int i = threadIdx.x; i < L / 4; i += 256) {
    fx4 v = xr[i];
    v = v + a;
    __builtin_nontemporal_store(v, &orow[i]);
  }
}

extern "C" void kernel_launch(void* const* d_in, const int* in_sizes, int n_in,
                              void* d_out, int out_size, void* d_ws, size_t ws_size,
                              hipStream_t stream) {
  const float* x   = (const float*)d_in[0];
  const float* cw  = (const float*)d_in[1];
  // d_in[2] (conv_mask_b) cancels exactly under softmax shift-invariance.
  const float* w1  = (const float*)d_in[3];
  const float* b1  = (const float*)d_in[4];
  const float* lnw = (const float*)d_in[5];
  const float* lnb = (const float*)d_in[6];
  const float* w2  = (const float*)d_in[7];
  const float* b2  = (const float*)d_in[8];
  float* out = (float*)d_out;

  char* ws = (char*)d_ws;
  float* part_pc  = (float*)ws;                                // B*NB*C = 1 MB
  float* part_m   = (float*)(ws + (size_t)B * NB * C * 4);
  float* part_z   = part_m + B * NB;
  float* add_term = part_z + B * NB;

  k_fused<<<dim3(NB, B), 1024, 0, stream>>>(x, cw, part_pc, part_m, part_z);
  k_tail<<<dim3(B), C, 0, stream>>>(part_pc, part_m, part_z,
                                    w1, b1, lnw, lnb, w2, b2, add_term);
  k_add<<<dim3(B * C), 256, 0, stream>>>(x, add_term, out);
}